// Round 1
// baseline (610.455 us; speedup 1.0000x reference)
//
#include <hip/hip_runtime.h>
#include <hip/hip_bf16.h>
#include <cstddef>

#define T_TOK 512
#define D_DIM 1024
#define E_EXP 64
#define INTER 512
#define TOPK 4

// ---------------- Router: 1 wave per token ----------------
__global__ __launch_bounds__(64) void router_kernel(
    const float* __restrict__ x, const float* __restrict__ gate_w,
    int* __restrict__ cnt, int* __restrict__ list, float* __restrict__ pairw) {
  const int t = blockIdx.x;
  const int e = threadIdx.x;  // 0..63, one expert per lane
  const float4* xr = (const float4*)(x + (size_t)t * D_DIM);
  const float4* gr = (const float4*)(gate_w + (size_t)e * D_DIM);
  float acc = 0.f;
#pragma unroll 8
  for (int i = 0; i < D_DIM / 4; i++) {
    float4 a = xr[i], b = gr[i];
    acc += a.x * b.x + a.y * b.y + a.z * b.z + a.w * b.w;
  }
  // softmax over 64 lanes
  float m = acc;
  for (int off = 32; off; off >>= 1) m = fmaxf(m, __shfl_xor(m, off, 64));
  float p = __expf(acc - m);
  float s = p;
  for (int off = 32; off; off >>= 1) s += __shfl_xor(s, off, 64);
  float prob = p / s;

  // top-4 via 4x butterfly argmax (all lanes converge to same result)
  float val = prob;
  int ids[TOPK];
  float ws[TOPK];
  float wsum = 0.f;
#pragma unroll
  for (int k = 0; k < TOPK; k++) {
    float v = val;
    int idx = e;
    for (int off = 32; off; off >>= 1) {
      float ov = __shfl_xor(v, off, 64);
      int oi = __shfl_xor(idx, off, 64);
      if (ov > v || (ov == v && oi < idx)) { v = ov; idx = oi; }
    }
    ids[k] = idx;
    ws[k] = v;
    wsum += v;
    if (e == idx) val = -1.f;  // exclude winner
  }
  if (e < TOPK) {
    const int k = e;
    const int ex = ids[k];
    const float w = ws[k] / wsum;  // renormalize
    const int p_id = t * TOPK + k;
    pairw[p_id] = w;
    const int pos = atomicAdd(&cnt[ex], 1);
    list[ex * T_TOK + pos] = p_id;
  }
}

// ---------------- Stage 1: gate+up GEMM + SiLU, fold combine weight ----------
// grid (E, INTER/BF1), block 256. Block tile: BF1=64 f-rows x BT=32 token slots.
#define BF1 64
#define BT1 32
#define BK1 32
__global__ __launch_bounds__(256) void stage1_kernel(
    const float* __restrict__ x, const float* __restrict__ w_gate,
    const float* __restrict__ w_up, const int* __restrict__ cnt,
    const int* __restrict__ list, const float* __restrict__ pairw,
    float* __restrict__ h) {
  const int e = blockIdx.x;
  const int fbase = blockIdx.y * BF1;
  const int n = cnt[e];
  if (n == 0) return;
  __shared__ float wg[BF1][BK1 + 1];
  __shared__ float wu[BF1][BK1 + 1];
  __shared__ float xt[BT1][BK1 + 1];
  const int tid = threadIdx.x;
  const int f0 = tid & 15;  // 16 f-groups, TF=4 (stride 16)
  const int t0 = tid >> 4;  // 16 t-groups, TT=2 (stride 16)
  const float* Wg = w_gate + ((size_t)e * INTER + fbase) * D_DIM;
  const float* Wu = w_up + ((size_t)e * INTER + fbase) * D_DIM;
  const int* mylist = list + e * T_TOK;

  for (int tb = 0; tb < n; tb += BT1) {
    float accg[4][2], accu[4][2];
#pragma unroll
    for (int i = 0; i < 4; i++)
#pragma unroll
      for (int j = 0; j < 2; j++) { accg[i][j] = 0.f; accu[i][j] = 0.f; }

    for (int kb = 0; kb < D_DIM; kb += BK1) {
      // stage W tiles: 64x32 each = 512 float4, 2 per thread
#pragma unroll
      for (int r = 0; r < 2; r++) {
        const int idx = tid + 256 * r;
        const int row = idx >> 3;
        const int col = (idx & 7) * 4;
        float4 vg = *(const float4*)(Wg + (size_t)row * D_DIM + kb + col);
        float4 vu = *(const float4*)(Wu + (size_t)row * D_DIM + kb + col);
        wg[row][col] = vg.x; wg[row][col + 1] = vg.y;
        wg[row][col + 2] = vg.z; wg[row][col + 3] = vg.w;
        wu[row][col] = vu.x; wu[row][col + 1] = vu.y;
        wu[row][col + 2] = vu.z; wu[row][col + 3] = vu.w;
      }
      // stage x tile: 32x32 = 256 float4, 1 per thread (gathered rows)
      {
        const int row = tid >> 3;
        const int col = (tid & 7) * 4;
        const int slot = tb + row;
        const int pid = mylist[slot < n ? slot : 0];
        const int tok = pid >> 2;
        float4 xv = *(const float4*)(x + (size_t)tok * D_DIM + kb + col);
        xt[row][col] = xv.x; xt[row][col + 1] = xv.y;
        xt[row][col + 2] = xv.z; xt[row][col + 3] = xv.w;
      }
      __syncthreads();
#pragma unroll
      for (int k = 0; k < BK1; k++) {
        float wgv[4], wuv[4], xv[2];
#pragma unroll
        for (int i = 0; i < 4; i++) {
          wgv[i] = wg[f0 + 16 * i][k];
          wuv[i] = wu[f0 + 16 * i][k];
        }
#pragma unroll
        for (int j = 0; j < 2; j++) xv[j] = xt[t0 + 16 * j][k];
#pragma unroll
        for (int i = 0; i < 4; i++)
#pragma unroll
          for (int j = 0; j < 2; j++) {
            accg[i][j] += wgv[i] * xv[j];
            accu[i][j] += wuv[i] * xv[j];
          }
      }
      __syncthreads();
    }
    // epilogue: h[p][f] = w_p * silu(g) * u
#pragma unroll
    for (int j = 0; j < 2; j++) {
      const int slot = tb + t0 + 16 * j;
      if (slot < n) {
        const int pid = mylist[slot];
        const float wp = pairw[pid];
        float* hp = h + (size_t)pid * INTER + fbase;
#pragma unroll
        for (int i = 0; i < 4; i++) {
          const float g = accg[i][j];
          const float u = accu[i][j];
          const float sg = g / (1.f + __expf(-g));
          hp[f0 + 16 * i] = wp * sg * u;
        }
      }
    }
  }
}

// ---------------- Stage 2: down GEMM, atomic accumulate into out ------------
// grid (E, D/BF2), block 256. Block tile: BF2=128 d-rows x BT=32 slots.
#define BF2 128
#define BT2 32
#define BK2 32
__global__ __launch_bounds__(256) void stage2_kernel(
    const float* __restrict__ w_down, const int* __restrict__ cnt,
    const int* __restrict__ list, const float* __restrict__ h,
    float* __restrict__ out) {
  const int e = blockIdx.x;
  const int dbase = blockIdx.y * BF2;
  const int n = cnt[e];
  if (n == 0) return;
  __shared__ float wd[BF2][BK2 + 1];
  __shared__ float ht[BT2][BK2 + 1];
  const int tid = threadIdx.x;
  const int f0 = tid & 31;  // 32 d-groups, TD=4 (stride 32)
  const int t0 = tid >> 5;  // 8 t-groups, TT=4 (stride 8)
  const float* Wd = w_down + ((size_t)e * D_DIM + dbase) * INTER;
  const int* mylist = list + e * T_TOK;

  for (int tb = 0; tb < n; tb += BT2) {
    float acc[4][4];
#pragma unroll
    for (int i = 0; i < 4; i++)
#pragma unroll
      for (int j = 0; j < 4; j++) acc[i][j] = 0.f;

    for (int kb = 0; kb < INTER; kb += BK2) {
      // stage Wd tile: 128x32 = 1024 float4, 4 per thread
#pragma unroll
      for (int r = 0; r < 4; r++) {
        const int idx = tid + 256 * r;
        const int row = idx >> 3;
        const int col = (idx & 7) * 4;
        float4 v = *(const float4*)(Wd + (size_t)row * INTER + kb + col);
        wd[row][col] = v.x; wd[row][col + 1] = v.y;
        wd[row][col + 2] = v.z; wd[row][col + 3] = v.w;
      }
      // stage h tile: 32x32 = 256 float4, 1 per thread (gathered rows)
      {
        const int row = tid >> 3;
        const int col = (tid & 7) * 4;
        const int slot = tb + row;
        const int pid = mylist[slot < n ? slot : 0];
        float4 v = *(const float4*)(h + (size_t)pid * INTER + kb + col);
        ht[row][col] = v.x; ht[row][col + 1] = v.y;
        ht[row][col + 2] = v.z; ht[row][col + 3] = v.w;
      }
      __syncthreads();
#pragma unroll
      for (int k = 0; k < BK2; k++) {
        float wv[4], hv[4];
#pragma unroll
        for (int i = 0; i < 4; i++) wv[i] = wd[f0 + 32 * i][k];
#pragma unroll
        for (int j = 0; j < 4; j++) hv[j] = ht[t0 + 8 * j][k];
#pragma unroll
        for (int i = 0; i < 4; i++)
#pragma unroll
          for (int j = 0; j < 4; j++) acc[i][j] += wv[i] * hv[j];
      }
      __syncthreads();
    }
    // epilogue: atomic accumulate (combine weight already folded into h)
#pragma unroll
    for (int j = 0; j < 4; j++) {
      const int slot = tb + t0 + 8 * j;
      if (slot < n) {
        const int tok = mylist[slot] >> 2;
        float* op = out + (size_t)tok * D_DIM + dbase;
#pragma unroll
        for (int i = 0; i < 4; i++) {
          atomicAdd(&op[f0 + 32 * i], acc[i][j]);
        }
      }
    }
  }
}

extern "C" void kernel_launch(void* const* d_in, const int* in_sizes, int n_in,
                              void* d_out, int out_size, void* d_ws, size_t ws_size,
                              hipStream_t stream) {
  const float* x = (const float*)d_in[0];       // [T, D]
  const float* gate_w = (const float*)d_in[1];  // [E, D]
  const float* w_gate = (const float*)d_in[2];  // [E, INTER, D]
  const float* w_up = (const float*)d_in[3];    // [E, INTER, D]
  const float* w_down = (const float*)d_in[4];  // [E, D, INTER]
  float* out = (float*)d_out;                   // [T, D]

  char* ws = (char*)d_ws;
  int* cnt = (int*)ws;                                     // E ints (256 B)
  int* list = (int*)(ws + 256);                            // E*T ints (128 KiB)
  float* pairw = (float*)(ws + 256 + E_EXP * T_TOK * 4);   // T*K floats (8 KiB)
  float* h = (float*)(ws + 256 + E_EXP * T_TOK * 4 + T_TOK * TOPK * 4);  // [T*K, INTER] 4 MiB

  hipMemsetAsync(cnt, 0, E_EXP * sizeof(int), stream);
  hipMemsetAsync(out, 0, (size_t)T_TOK * D_DIM * sizeof(float), stream);

  router_kernel<<<T_TOK, 64, 0, stream>>>(x, gate_w, cnt, list, pairw);
  stage1_kernel<<<dim3(E_EXP, INTER / BF1), 256, 0, stream>>>(
      x, w_gate, w_up, cnt, list, pairw, h);
  stage2_kernel<<<dim3(E_EXP, D_DIM / BF2), 256, 0, stream>>>(
      w_down, cnt, list, h, out);
}

// Round 2
// 539.770 us; speedup vs baseline: 1.1310x; 1.1310x over previous
//
#include <hip/hip_runtime.h>
#include <hip/hip_bf16.h>
#include <cstddef>

#define T_TOK 512
#define D_DIM 1024
#define E_EXP 64
#define INTER 512
#define TOPK 4

// ---------------- Router: 1 wave per token ----------------
__global__ __launch_bounds__(64) void router_kernel(
    const float* __restrict__ x, const float* __restrict__ gate_w,
    int* __restrict__ cnt, int* __restrict__ list, float* __restrict__ pairw) {
  const int t = blockIdx.x;
  const int e = threadIdx.x;  // 0..63, one expert per lane
  const float4* xr = (const float4*)(x + (size_t)t * D_DIM);
  const float4* gr = (const float4*)(gate_w + (size_t)e * D_DIM);
  float acc = 0.f;
#pragma unroll 8
  for (int i = 0; i < D_DIM / 4; i++) {
    float4 a = xr[i], b = gr[i];
    acc += a.x * b.x + a.y * b.y + a.z * b.z + a.w * b.w;
  }
  // softmax over 64 lanes
  float m = acc;
  for (int off = 32; off; off >>= 1) m = fmaxf(m, __shfl_xor(m, off, 64));
  float p = __expf(acc - m);
  float s = p;
  for (int off = 32; off; off >>= 1) s += __shfl_xor(s, off, 64);
  float prob = p / s;

  // top-4 via 4x butterfly argmax
  float val = prob;
  int ids[TOPK];
  float ws[TOPK];
  float wsum = 0.f;
#pragma unroll
  for (int k = 0; k < TOPK; k++) {
    float v = val;
    int idx = e;
    for (int off = 32; off; off >>= 1) {
      float ov = __shfl_xor(v, off, 64);
      int oi = __shfl_xor(idx, off, 64);
      if (ov > v || (ov == v && oi < idx)) { v = ov; idx = oi; }
    }
    ids[k] = idx;
    ws[k] = v;
    wsum += v;
    if (e == idx) val = -1.f;
  }
  if (e < TOPK) {
    const int k = e;
    const int ex = ids[k];
    const float w = ws[k] / wsum;
    const int p_id = t * TOPK + k;
    pairw[p_id] = w;
    const int pos = atomicAdd(&cnt[ex], 1);
    list[ex * T_TOK + pos] = p_id;
  }
}

// ---------------- Stage 1: gate+up GEMM + SiLU ----------------
// grid (E=64, INTER/BF1=16) = 1024 blocks, 128 threads (2 waves).
// Block tile BF1=32 f-rows x BT1=32 token slots, BK1=64.
// Thread grid 8(f) x 16(t); thread tile 4f x 2t (f = f0+8i, t = t0+16j).
// LDS rows padded to 68 floats: quad-stride 17 == 1 mod 8 -> balanced b128.
#define BF1 32
#define BT1 32
#define BK1 64
#define LD1 (BK1 + 4)
__global__ __launch_bounds__(128) void stage1_kernel(
    const float* __restrict__ x, const float* __restrict__ w_gate,
    const float* __restrict__ w_up, const int* __restrict__ cnt,
    const int* __restrict__ list, const float* __restrict__ pairw,
    float* __restrict__ h) {
  const int e = blockIdx.x;
  const int fbase = blockIdx.y * BF1;
  const int n = cnt[e];
  if (n == 0) return;
  __shared__ float wg[BF1][LD1];
  __shared__ float wu[BF1][LD1];
  __shared__ float xt[BT1][LD1];
  const int tid = threadIdx.x;
  const int f0 = tid & 7;
  const int t0 = tid >> 3;  // 0..15
  const float* Wg = w_gate + ((size_t)e * INTER + fbase) * D_DIM;
  const float* Wu = w_up + ((size_t)e * INTER + fbase) * D_DIM;
  const int* mylist = list + e * T_TOK;

  for (int tb = 0; tb < n; tb += BT1) {
    float accg[4][2], accu[4][2];
#pragma unroll
    for (int i = 0; i < 4; i++)
#pragma unroll
      for (int j = 0; j < 2; j++) { accg[i][j] = 0.f; accu[i][j] = 0.f; }

    for (int kb = 0; kb < D_DIM; kb += BK1) {
      // stage W tiles: 32x64 each = 512 float4, 4 per thread
#pragma unroll
      for (int r = 0; r < 4; r++) {
        const int idx = tid + 128 * r;
        const int row = idx >> 4;
        const int c4 = (idx & 15) << 2;
        float4 vg = *(const float4*)(Wg + (size_t)row * D_DIM + kb + c4);
        float4 vu = *(const float4*)(Wu + (size_t)row * D_DIM + kb + c4);
        *(float4*)&wg[row][c4] = vg;
        *(float4*)&wu[row][c4] = vu;
      }
      // stage x tile: 32x64 = 512 float4, 4 per thread (gathered rows)
#pragma unroll
      for (int r = 0; r < 4; r++) {
        const int idx = tid + 128 * r;
        const int row = idx >> 4;
        const int c4 = (idx & 15) << 2;
        const int slot = tb + row;
        const int pid = mylist[slot < n ? slot : 0];
        const int tok = pid >> 2;
        *(float4*)&xt[row][c4] = *(const float4*)(x + (size_t)tok * D_DIM + kb + c4);
      }
      __syncthreads();
#pragma unroll
      for (int k4 = 0; k4 < BK1; k4 += 4) {
        float4 wgv[4], wuv[4], xv[2];
#pragma unroll
        for (int i = 0; i < 4; i++) {
          wgv[i] = *(const float4*)&wg[f0 + 8 * i][k4];
          wuv[i] = *(const float4*)&wu[f0 + 8 * i][k4];
        }
#pragma unroll
        for (int j = 0; j < 2; j++) xv[j] = *(const float4*)&xt[t0 + 16 * j][k4];
#pragma unroll
        for (int kk = 0; kk < 4; kk++) {
#pragma unroll
          for (int i = 0; i < 4; i++) {
            const float a = ((const float*)&wgv[i])[kk];
            const float b = ((const float*)&wuv[i])[kk];
#pragma unroll
            for (int j = 0; j < 2; j++) {
              const float xx = ((const float*)&xv[j])[kk];
              accg[i][j] += a * xx;
              accu[i][j] += b * xx;
            }
          }
        }
      }
      __syncthreads();
    }
    // epilogue: h[p][f] = w_p * silu(g) * u
#pragma unroll
    for (int j = 0; j < 2; j++) {
      const int slot = tb + t0 + 16 * j;
      if (slot < n) {
        const int pid = mylist[slot];
        const float wp = pairw[pid];
        float* hp = h + (size_t)pid * INTER + fbase;
#pragma unroll
        for (int i = 0; i < 4; i++) {
          const float g = accg[i][j];
          const float u = accu[i][j];
          const float sg = g / (1.f + __expf(-g));
          hp[f0 + 8 * i] = wp * sg * u;
        }
      }
    }
  }
}

// ---------------- Stage 2: down GEMM, atomic accumulate ----------------
// grid (E=64, D/BF2=16) = 1024 blocks, 128 threads.
// Block tile BF2=64 d-rows x BT2=32 slots, BK2=64.
// Thread grid 16(d) x 8(t); thread tile 4d x 4t (d = d0+16i, t = t0+8j).
#define BF2 64
#define BT2 32
#define BK2 64
#define LD2 (BK2 + 4)
__global__ __launch_bounds__(128) void stage2_kernel(
    const float* __restrict__ w_down, const int* __restrict__ cnt,
    const int* __restrict__ list, const float* __restrict__ h,
    float* __restrict__ out) {
  const int e = blockIdx.x;
  const int dbase = blockIdx.y * BF2;
  const int n = cnt[e];
  if (n == 0) return;
  __shared__ float wd[BF2][LD2];
  __shared__ float ht[BT2][LD2];
  const int tid = threadIdx.x;
  const int d0 = tid & 15;
  const int t0 = tid >> 4;  // 0..7
  const float* Wd = w_down + ((size_t)e * D_DIM + dbase) * INTER;
  const int* mylist = list + e * T_TOK;

  for (int tb = 0; tb < n; tb += BT2) {
    float acc[4][4];
#pragma unroll
    for (int i = 0; i < 4; i++)
#pragma unroll
      for (int j = 0; j < 4; j++) acc[i][j] = 0.f;

    for (int kb = 0; kb < INTER; kb += BK2) {
      // stage Wd tile: 64x64 = 1024 float4, 8 per thread
#pragma unroll
      for (int r = 0; r < 8; r++) {
        const int idx = tid + 128 * r;
        const int row = idx >> 4;
        const int c4 = (idx & 15) << 2;
        float4 v = *(const float4*)(Wd + (size_t)row * INTER + kb + c4);
        *(float4*)&wd[row][c4] = v;
      }
      // stage h tile: 32x64 = 512 float4, 4 per thread (gathered rows)
#pragma unroll
      for (int r = 0; r < 4; r++) {
        const int idx = tid + 128 * r;
        const int row = idx >> 4;
        const int c4 = (idx & 15) << 2;
        const int slot = tb + row;
        const int pid = mylist[slot < n ? slot : 0];
        *(float4*)&ht[row][c4] = *(const float4*)(h + (size_t)pid * INTER + kb + c4);
      }
      __syncthreads();
#pragma unroll
      for (int k4 = 0; k4 < BK2; k4 += 4) {
        float4 wv[4], hv[4];
#pragma unroll
        for (int i = 0; i < 4; i++) wv[i] = *(const float4*)&wd[d0 + 16 * i][k4];
#pragma unroll
        for (int j = 0; j < 4; j++) hv[j] = *(const float4*)&ht[t0 + 8 * j][k4];
#pragma unroll
        for (int kk = 0; kk < 4; kk++) {
#pragma unroll
          for (int i = 0; i < 4; i++) {
            const float a = ((const float*)&wv[i])[kk];
#pragma unroll
            for (int j = 0; j < 4; j++) {
              acc[i][j] += a * ((const float*)&hv[j])[kk];
            }
          }
        }
      }
      __syncthreads();
    }
    // epilogue: atomic accumulate (combine weight folded into h)
#pragma unroll
    for (int j = 0; j < 4; j++) {
      const int slot = tb + t0 + 8 * j;
      if (slot < n) {
        const int tok = mylist[slot] >> 2;
        float* op = out + (size_t)tok * D_DIM + dbase;
#pragma unroll
        for (int i = 0; i < 4; i++) {
          atomicAdd(&op[d0 + 16 * i], acc[i][j]);
        }
      }
    }
  }
}

extern "C" void kernel_launch(void* const* d_in, const int* in_sizes, int n_in,
                              void* d_out, int out_size, void* d_ws, size_t ws_size,
                              hipStream_t stream) {
  const float* x = (const float*)d_in[0];       // [T, D]
  const float* gate_w = (const float*)d_in[1];  // [E, D]
  const float* w_gate = (const float*)d_in[2];  // [E, INTER, D]
  const float* w_up = (const float*)d_in[3];    // [E, INTER, D]
  const float* w_down = (const float*)d_in[4];  // [E, D, INTER]
  float* out = (float*)d_out;                   // [T, D]

  char* ws = (char*)d_ws;
  int* cnt = (int*)ws;                                     // E ints
  int* list = (int*)(ws + 256);                            // E*T ints
  float* pairw = (float*)(ws + 256 + E_EXP * T_TOK * 4);   // T*K floats
  float* h = (float*)(ws + 256 + E_EXP * T_TOK * 4 + T_TOK * TOPK * 4);  // [T*K, INTER]

  hipMemsetAsync(cnt, 0, E_EXP * sizeof(int), stream);
  hipMemsetAsync(out, 0, (size_t)T_TOK * D_DIM * sizeof(float), stream);

  router_kernel<<<T_TOK, 64, 0, stream>>>(x, gate_w, cnt, list, pairw);
  stage1_kernel<<<dim3(E_EXP, INTER / BF1), 128, 0, stream>>>(
      x, w_gate, w_up, cnt, list, pairw, h);
  stage2_kernel<<<dim3(E_EXP, D_DIM / BF2), 128, 0, stream>>>(
      w_down, cnt, list, h, out);
}